// Round 4
// baseline (118.707 us; speedup 1.0000x reference)
//
#include <hip/hip_runtime.h>
#include <hip/hip_cooperative_groups.h>

namespace cg = cooperative_groups;

#define EDIM 10
#define CDIM 128
#define DDIM 9
#define BDIM 512
#define NT3 165   // #(a<=b<=c) triples over 9 dims
#define NT2 45    // #(a<=b) pairs
#define NT1 9
#define NT (NT3 + NT2 + NT1)  // 219
#define NCHUNK 72             // exact worst case: sum ceil(n_e/8) <= (512+70)/8
#define NBLOCKS (NCHUNK * 4)  // 288
#define NTHREADS (NBLOCKS * 256)        // 73728
#define TOT_ITEMS (EDIM * NT * CDIM)    // 280320 table entries

// ws layout:
//   T:        [EDIM][NT][CDIM][4] float   (~4.49 MB)   (t-major, c inner: coalesced)
//   sortedB:  int[BDIM]
//   chunkE/S/C: int[NCHUNK] each
#define TABLE_FLOATS ((size_t)EDIM * NT * CDIM * 4)

union ShMem {
  struct { int es[BDIM]; int cnt[EDIM]; int st[EDIM]; int rk[EDIM]; } bk;
  float xs[4][576];  // per-wave staging: 8 b-segs x (8 c x 9 d)
};

// ---------------------------------------------------------------------------
// device helpers
// ---------------------------------------------------------------------------
__device__ __forceinline__ void table_item(
    int item,
    const float* __restrict__ u1_0e, const float* __restrict__ w1_0e,
    const float* __restrict__ u2_0e, const float* __restrict__ w2_0e,
    const float* __restrict__ u3_0e, const float* __restrict__ w3_0e,
    const float* __restrict__ u1_1o, const float* __restrict__ w1_1o,
    const float* __restrict__ u2_1o, const float* __restrict__ w2_1o,
    const float* __restrict__ u3_1o, const float* __restrict__ w3_1o,
    float* __restrict__ T) {
  const int c = item & (CDIM - 1);
  const int tt = item >> 7;       // 0..2189
  const int e = tt / NT;
  const int t = tt - e * NT;

  float o0 = 0.f, o1 = 0.f, o2 = 0.f, o3 = 0.f;

  if (t < NT3) {
    int r = t, a = 0, b = 0;
    for (a = 0; a < DDIM; ++a) {
      int n = (DDIM - a) * (DDIM - a + 1) / 2;
      if (r < n) break;
      r -= n;
    }
    for (b = a; b < DDIM; ++b) {
      int n = DDIM - b;
      if (r < n) break;
      r -= n;
    }
    const int cc = b + r;
    const float mult = (a == b && b == cc) ? 1.f : ((a == b || b == cc) ? 3.f : 6.f);

    const int ub0 = ((a * DDIM + b) * DDIM + cc) * 8;       // u3_0e: (9,9,9,8,1)
    for (int k = 0; k < 8; ++k)
      o0 += u3_0e[ub0 + k] * w3_0e[(k * EDIM + e) * CDIM + c];

    const int ub1 = ((a * DDIM + b) * DDIM + cc) * 12 * 3;  // u3_1o: (9,9,9,12,3)
    for (int k = 0; k < 12; ++k) {
      const float wv = w3_1o[(k * EDIM + e) * CDIM + c];
      o1 += u3_1o[ub1 + k * 3 + 0] * wv;
      o2 += u3_1o[ub1 + k * 3 + 1] * wv;
      o3 += u3_1o[ub1 + k * 3 + 2] * wv;
    }
    o0 *= mult; o1 *= mult; o2 *= mult; o3 *= mult;
  } else if (t < NT3 + NT2) {
    int r = t - NT3, a = 0;
    for (a = 0; a < DDIM; ++a) {
      int n = DDIM - a;
      if (r < n) break;
      r -= n;
    }
    const int b = a + r;
    const float mult = (a == b) ? 1.f : 2.f;

    const int ub0 = (a * DDIM + b) * 3;                     // u2_0e: (9,9,3,1)
    for (int k = 0; k < 3; ++k)
      o0 += u2_0e[ub0 + k] * w2_0e[(k * EDIM + e) * CDIM + c];

    const int ub1 = (a * DDIM + b) * 4 * 3;                 // u2_1o: (9,9,4,3)
    for (int k = 0; k < 4; ++k) {
      const float wv = w2_1o[(k * EDIM + e) * CDIM + c];
      o1 += u2_1o[ub1 + k * 3 + 0] * wv;
      o2 += u2_1o[ub1 + k * 3 + 1] * wv;
      o3 += u2_1o[ub1 + k * 3 + 2] * wv;
    }
    o0 *= mult; o1 *= mult; o2 *= mult; o3 *= mult;
  } else {
    const int j = t - NT3 - NT2;
    o0 = u1_0e[j] * w1_0e[e * CDIM + c];                    // u1_0e: (9,1,1)
    const float wv = w1_1o[e * CDIM + c];
    o1 = u1_1o[j * 3 + 0] * wv;                             // u1_1o: (9,1,3)
    o2 = u1_1o[j * 3 + 1] * wv;
    o3 = u1_1o[j * 3 + 2] * wv;
  }

  float4* dst = reinterpret_cast<float4*>(T) + (size_t)(e * NT + t) * CDIM + c;
  *dst = make_float4(o0, o1, o2, o3);
}

__device__ __forceinline__ void bucket_block(
    ShMem* sh, const float* __restrict__ y, int* __restrict__ sortedB,
    int* __restrict__ chunkE, int* __restrict__ chunkS, int* __restrict__ chunkC) {
  const int tid = threadIdx.x;
  if (tid < EDIM) { sh->bk.cnt[tid] = 0; sh->bk.rk[tid] = 0; }
  __syncthreads();
  for (int b = tid; b < BDIM; b += 256) {
    int e = 0;
    for (int q = 0; q < EDIM; ++q)
      if (y[b * EDIM + q] > 0.5f) e = q;
    sh->bk.es[b] = e;
    atomicAdd(&sh->bk.cnt[e], 1);
  }
  __syncthreads();
  if (tid == 0) {
    int s = 0, ci = 0;
    for (int e = 0; e < EDIM; ++e) {
      sh->bk.st[e] = s;
      const int n = sh->bk.cnt[e];
      for (int j = 0; j < n; j += 8) {
        chunkE[ci] = e;
        chunkS[ci] = s + j;
        chunkC[ci] = (n - j < 8) ? (n - j) : 8;
        ++ci;
      }
      s += n;
    }
    for (; ci < NCHUNK; ++ci) chunkC[ci] = 0;
  }
  __syncthreads();
  for (int b = tid; b < BDIM; b += 256) {
    const int e = sh->bk.es[b];
    const int r = atomicAdd(&sh->bk.rk[e], 1);
    sortedB[sh->bk.st[e] + r] = b;
  }
}

__device__ __forceinline__ void phaseB(
    ShMem* sh, const float* __restrict__ x, const float* __restrict__ T,
    const int* __restrict__ sortedB, const int* __restrict__ chunkE,
    const int* __restrict__ chunkS, const int* __restrict__ chunkC,
    float* __restrict__ out) {
  const int bid = blockIdx.x;
  const int chunk = bid >> 2;   // 0..71
  const int quad = bid & 3;
  const int cnt = chunkC[chunk];
  if (cnt == 0) return;
  const int e = chunkE[chunk];
  const int start = chunkS[chunk];

  const int tid = threadIdx.x;
  const int wv = tid >> 6;
  const int lane = tid & 63;
  const int cl = lane & 7;
  const int slot = lane >> 3;
  const int ctile = quad * 4 + wv;      // 0..15
  const int c = ctile * 8 + cl;

  const int sl = (slot < cnt) ? slot : (cnt - 1);
  const bool valid = (slot < cnt);
  const int b = sortedB[start + sl];

  // ---- cooperative x staging: wave stages 8 b-rows x 8 channels x 9 d ----
  // seg == slot for this lane; 18 aligned float4 per seg, 8 lanes per seg.
  {
    const int j = lane & 7;   // within-seg float4 cursor (cl doubles as j)
    const float4* gbase = reinterpret_cast<const float4*>(
        x + ((size_t)b * CDIM + ctile * 8) * DDIM);  // 16B-aligned: b*4608 + ctile*288
    float4* xf4 = reinterpret_cast<float4*>(&sh->xs[wv][0]);
    xf4[slot * 18 + j] = gbase[j];
    xf4[slot * 18 + j + 8] = gbase[j + 8];
    if (j < 2) xf4[slot * 18 + j + 16] = gbase[j + 16];
  }
  __syncthreads();

  float xv[DDIM];
#pragma unroll
  for (int d = 0; d < DDIM; ++d)
    xv[d] = sh->xs[wv][slot * 72 + cl * 9 + d];  // lane*9+d -> 2 lanes/bank, free

  const float4* Tb = reinterpret_cast<const float4*>(T) + (size_t)e * NT * CDIM + c;

  float a0 = 0.f, a1 = 0.f, a2 = 0.f, a3 = 0.f;
  int t = 0;

  // order 3: a<=b2<=c3 (same enumeration order as the table build)
#pragma unroll
  for (int a = 0; a < DDIM; ++a) {
#pragma unroll
    for (int b2 = a; b2 < DDIM; ++b2) {
      const float xab = xv[a] * xv[b2];
#pragma unroll
      for (int c3 = b2; c3 < DDIM; ++c3) {
        const float m = xab * xv[c3];
        const float4 tv = Tb[(size_t)t * CDIM];
        a0 = fmaf(tv.x, m, a0);
        a1 = fmaf(tv.y, m, a1);
        a2 = fmaf(tv.z, m, a2);
        a3 = fmaf(tv.w, m, a3);
        ++t;
      }
    }
  }
  // order 2
#pragma unroll
  for (int a = 0; a < DDIM; ++a) {
#pragma unroll
    for (int b2 = a; b2 < DDIM; ++b2) {
      const float m = xv[a] * xv[b2];
      const float4 tv = Tb[(size_t)t * CDIM];
      a0 = fmaf(tv.x, m, a0);
      a1 = fmaf(tv.y, m, a1);
      a2 = fmaf(tv.z, m, a2);
      a3 = fmaf(tv.w, m, a3);
      ++t;
    }
  }
  // order 1
#pragma unroll
  for (int j = 0; j < DDIM; ++j) {
    const float m = xv[j];
    const float4 tv = Tb[(size_t)t * CDIM];
    a0 = fmaf(tv.x, m, a0);
    a1 = fmaf(tv.y, m, a1);
    a2 = fmaf(tv.z, m, a2);
    a3 = fmaf(tv.w, m, a3);
    ++t;
  }

  if (valid) {
    float4* o = reinterpret_cast<float4*>(out) + ((size_t)b * CDIM + c);
    *o = make_float4(a0, a1, a2, a3);
  }
}

// ---------------------------------------------------------------------------
// Fused cooperative kernel: phase A (table + bucketing), grid sync, phase B.
// ---------------------------------------------------------------------------
__global__ __launch_bounds__(256, 2) void symcon_fused_kernel(
    const float* x, const float* y,
    const float* u1_0e, const float* w1_0e,
    const float* u2_0e, const float* w2_0e,
    const float* u3_0e, const float* w3_0e,
    const float* u1_1o, const float* w1_1o,
    const float* u2_1o, const float* w2_1o,
    const float* u3_1o, const float* w3_1o,
    float* T, int* sortedB, int* chunkE, int* chunkS, int* chunkC,
    float* out) {
  __shared__ ShMem sh;
  const int bid = blockIdx.x;
  const int gid = bid * 256 + threadIdx.x;

  if (bid == 0)
    bucket_block(&sh, y, sortedB, chunkE, chunkS, chunkC);

#pragma unroll
  for (int k = 0; k < 4; ++k) {
    const int item = gid + k * NTHREADS;
    if (item < TOT_ITEMS)
      table_item(item, u1_0e, w1_0e, u2_0e, w2_0e, u3_0e, w3_0e,
                 u1_1o, w1_1o, u2_1o, w2_1o, u3_1o, w3_1o, T);
  }

  __threadfence();            // make T / bucket arrays device-visible
  cg::this_grid().sync();
  __syncthreads();            // re-converge block before shared-mem reuse

  phaseB(&sh, x, T, sortedB, chunkE, chunkS, chunkC, out);
}

// ---------------------------------------------------------------------------
// Fallback split kernels (used if cooperative enqueue is rejected)
// ---------------------------------------------------------------------------
__global__ __launch_bounds__(256, 2) void phaseA_kernel(
    const float* y,
    const float* u1_0e, const float* w1_0e,
    const float* u2_0e, const float* w2_0e,
    const float* u3_0e, const float* w3_0e,
    const float* u1_1o, const float* w1_1o,
    const float* u2_1o, const float* w2_1o,
    const float* u3_1o, const float* w3_1o,
    float* T, int* sortedB, int* chunkE, int* chunkS, int* chunkC) {
  __shared__ ShMem sh;
  const int bid = blockIdx.x;
  const int gid = bid * 256 + threadIdx.x;
  if (bid == 0)
    bucket_block(&sh, y, sortedB, chunkE, chunkS, chunkC);
#pragma unroll
  for (int k = 0; k < 4; ++k) {
    const int item = gid + k * NTHREADS;
    if (item < TOT_ITEMS)
      table_item(item, u1_0e, w1_0e, u2_0e, w2_0e, u3_0e, w3_0e,
                 u1_1o, w1_1o, u2_1o, w2_1o, u3_1o, w3_1o, T);
  }
}

__global__ __launch_bounds__(256, 2) void phaseB_kernel(
    const float* x, const float* T, const int* sortedB, const int* chunkE,
    const int* chunkS, const int* chunkC, float* out) {
  __shared__ ShMem sh;
  phaseB(&sh, x, T, sortedB, chunkE, chunkS, chunkC, out);
}

extern "C" void kernel_launch(void* const* d_in, const int* in_sizes, int n_in,
                              void* d_out, int out_size, void* d_ws, size_t ws_size,
                              hipStream_t stream) {
  const float* x     = (const float*)d_in[0];
  const float* y     = (const float*)d_in[1];
  const float* u1_0e = (const float*)d_in[2];
  const float* w1_0e = (const float*)d_in[3];
  const float* u2_0e = (const float*)d_in[4];
  const float* w2_0e = (const float*)d_in[5];
  const float* u3_0e = (const float*)d_in[6];
  const float* w3_0e = (const float*)d_in[7];
  const float* u1_1o = (const float*)d_in[8];
  const float* w1_1o = (const float*)d_in[9];
  const float* u2_1o = (const float*)d_in[10];
  const float* w2_1o = (const float*)d_in[11];
  const float* u3_1o = (const float*)d_in[12];
  const float* w3_1o = (const float*)d_in[13];

  float* T = (float*)d_ws;
  int* sortedB = (int*)((float*)d_ws + TABLE_FLOATS);
  int* chunkE = sortedB + BDIM;
  int* chunkS = chunkE + NCHUNK;
  int* chunkC = chunkS + NCHUNK;
  float* out = (float*)d_out;

  const size_t need = TABLE_FLOATS * sizeof(float) +
                      (BDIM + 3 * NCHUNK) * sizeof(int);
  if (ws_size < need) return;

  void* kargs[] = {
      (void*)&x, (void*)&y,
      (void*)&u1_0e, (void*)&w1_0e, (void*)&u2_0e, (void*)&w2_0e,
      (void*)&u3_0e, (void*)&w3_0e, (void*)&u1_1o, (void*)&w1_1o,
      (void*)&u2_1o, (void*)&w2_1o, (void*)&u3_1o, (void*)&w3_1o,
      (void*)&T, (void*)&sortedB, (void*)&chunkE, (void*)&chunkS, (void*)&chunkC,
      (void*)&out};

  hipError_t err = hipLaunchCooperativeKernel(
      (const void*)symcon_fused_kernel, dim3(NBLOCKS), dim3(256), kargs, 0, stream);

  if (err != hipSuccess) {
    // deterministic fallback: two ordinary launches on the same stream
    hipLaunchKernelGGL(phaseA_kernel, dim3(NBLOCKS), dim3(256), 0, stream,
                       y, u1_0e, w1_0e, u2_0e, w2_0e, u3_0e, w3_0e,
                       u1_1o, w1_1o, u2_1o, w2_1o, u3_1o, w3_1o,
                       T, sortedB, chunkE, chunkS, chunkC);
    hipLaunchKernelGGL(phaseB_kernel, dim3(NBLOCKS), dim3(256), 0, stream,
                       x, T, sortedB, chunkE, chunkS, chunkC, out);
  }
}

// Round 5
// 26.518 us; speedup vs baseline: 4.4764x; 4.4764x over previous
//
#include <hip/hip_runtime.h>

#define EDIM 10
#define CDIM 128
#define DDIM 9
#define BDIM 512
#define NT3 165   // #(a<=b<=c) triples over 9 dims
#define NT2 45    // #(a<=b) pairs
#define NT1 9
#define NT (NT3 + NT2 + NT1)  // 219

// ws layout:
//   T:        [EDIM][NT][CDIM][4] float   (~4.49 MB)  (t-major, c inner: coalesced)
//   sortedB:  int[BDIM]   (rows sorted by species, any order within species)
//   es:       int[BDIM]   (species per row)
#define TABLE_FLOATS ((size_t)EDIM * NT * CDIM * 4)

// ---------------------------------------------------------------------------
// Kernel A: blocks 0..EDIM*NT-1 build the coefficient table (one (e,t) per
// block, 128 channels per thread-row — coalesced float4 store). Block
// EDIM*NT does species bucketing with NO serial chunk construction:
// counting + LDS atomics + a 10-iteration prefix only.
// ---------------------------------------------------------------------------
__global__ __launch_bounds__(CDIM) void table_bucket_kernel(
    const float* __restrict__ u1_0e, const float* __restrict__ w1_0e,
    const float* __restrict__ u2_0e, const float* __restrict__ w2_0e,
    const float* __restrict__ u3_0e, const float* __restrict__ w3_0e,
    const float* __restrict__ u1_1o, const float* __restrict__ w1_1o,
    const float* __restrict__ u2_1o, const float* __restrict__ w2_1o,
    const float* __restrict__ u3_1o, const float* __restrict__ w3_1o,
    const float* __restrict__ y,
    float* __restrict__ T, int* __restrict__ sortedB, int* __restrict__ esg) {
  if (blockIdx.x == EDIM * NT) {
    // ---- species bucketing: 128 threads x 4 rows each ----
    __shared__ int cnt[EDIM];
    __shared__ int st[EDIM];
    __shared__ int rk[EDIM];
    const int tid = threadIdx.x;
    if (tid < EDIM) { cnt[tid] = 0; rk[tid] = 0; }
    __syncthreads();
    int mye[4];
#pragma unroll
    for (int k = 0; k < 4; ++k) {
      const int b = tid + 128 * k;
      int e = 0;
      for (int q = 0; q < EDIM; ++q)
        if (y[b * EDIM + q] > 0.5f) e = q;
      mye[k] = e;
      esg[b] = e;
      atomicAdd(&cnt[e], 1);
    }
    __syncthreads();
    if (tid == 0) {
      int s = 0;
      for (int e = 0; e < EDIM; ++e) { st[e] = s; s += cnt[e]; }
    }
    __syncthreads();
#pragma unroll
    for (int k = 0; k < 4; ++k) {
      const int b = tid + 128 * k;
      const int e = mye[k];
      const int r = atomicAdd(&rk[e], 1);
      sortedB[st[e] + r] = b;   // order within species irrelevant
    }
    return;
  }

  // ---- table build (round-2 verified layout/order) ----
  const int c = threadIdx.x;           // channel
  const int blk = blockIdx.x;          // e * NT + t
  const int e = blk / NT;
  const int t = blk - e * NT;

  float o0 = 0.f, o1 = 0.f, o2 = 0.f, o3 = 0.f;

  if (t < NT3) {
    int r = t, a = 0, b = 0;
    for (a = 0; a < DDIM; ++a) {
      int n = (DDIM - a) * (DDIM - a + 1) / 2;
      if (r < n) break;
      r -= n;
    }
    for (b = a; b < DDIM; ++b) {
      int n = DDIM - b;
      if (r < n) break;
      r -= n;
    }
    const int cc = b + r;
    const float mult = (a == b && b == cc) ? 1.f : ((a == b || b == cc) ? 3.f : 6.f);

    const int ub0 = ((a * DDIM + b) * DDIM + cc) * 8;       // u3_0e: (9,9,9,8,1)
    for (int k = 0; k < 8; ++k)
      o0 += u3_0e[ub0 + k] * w3_0e[(k * EDIM + e) * CDIM + c];

    const int ub1 = ((a * DDIM + b) * DDIM + cc) * 12 * 3;  // u3_1o: (9,9,9,12,3)
    for (int k = 0; k < 12; ++k) {
      const float wv = w3_1o[(k * EDIM + e) * CDIM + c];
      o1 += u3_1o[ub1 + k * 3 + 0] * wv;
      o2 += u3_1o[ub1 + k * 3 + 1] * wv;
      o3 += u3_1o[ub1 + k * 3 + 2] * wv;
    }
    o0 *= mult; o1 *= mult; o2 *= mult; o3 *= mult;
  } else if (t < NT3 + NT2) {
    int r = t - NT3, a = 0;
    for (a = 0; a < DDIM; ++a) {
      int n = DDIM - a;
      if (r < n) break;
      r -= n;
    }
    const int b = a + r;
    const float mult = (a == b) ? 1.f : 2.f;

    const int ub0 = (a * DDIM + b) * 3;                     // u2_0e: (9,9,3,1)
    for (int k = 0; k < 3; ++k)
      o0 += u2_0e[ub0 + k] * w2_0e[(k * EDIM + e) * CDIM + c];

    const int ub1 = (a * DDIM + b) * 4 * 3;                 // u2_1o: (9,9,4,3)
    for (int k = 0; k < 4; ++k) {
      const float wv = w2_1o[(k * EDIM + e) * CDIM + c];
      o1 += u2_1o[ub1 + k * 3 + 0] * wv;
      o2 += u2_1o[ub1 + k * 3 + 1] * wv;
      o3 += u2_1o[ub1 + k * 3 + 2] * wv;
    }
    o0 *= mult; o1 *= mult; o2 *= mult; o3 *= mult;
  } else {
    const int j = t - NT3 - NT2;
    o0 = u1_0e[j] * w1_0e[e * CDIM + c];                    // u1_0e: (9,1,1)
    const float wv = w1_1o[e * CDIM + c];
    o1 = u1_1o[j * 3 + 0] * wv;                             // u1_1o: (9,1,3)
    o2 = u1_1o[j * 3 + 1] * wv;
    o3 = u1_1o[j * 3 + 2] * wv;
  }

  float4* dst = reinterpret_cast<float4*>(T) + (size_t)(e * NT + t) * CDIM + c;
  *dst = make_float4(o0, o1, o2, o3);
}

// ---------------------------------------------------------------------------
// Kernel B: 256 blocks x 256 threads. Block (chunk,quad): chunk j owns sorted
// rows [8j,8j+8) (mostly one species -> wave-level same-address dedup of
// table reads). Wave = 8 channels x 8 slots. x staged via coalesced float4.
// ---------------------------------------------------------------------------
__global__ __launch_bounds__(256) void symcon_main_kernel(
    const float* __restrict__ x, const float* __restrict__ T,
    const int* __restrict__ sortedB, const int* __restrict__ esg,
    float* __restrict__ out) {
  __shared__ float xs[4][576];  // per-wave: 8 slots x (8 c x 9 d)

  const int bid = blockIdx.x;
  const int chunk = bid >> 2;          // 0..63
  const int quad = bid & 3;
  const int tid = threadIdx.x;
  const int wv = tid >> 6;
  const int lane = tid & 63;
  const int cl = lane & 7;
  const int slot = lane >> 3;
  const int ctile = quad * 4 + wv;     // 0..15
  const int c = ctile * 8 + cl;
  const int row = chunk * 8 + slot;    // < 512 always
  const int b = sortedB[row];
  const int e = esg[b];

  // ---- cooperative x staging: slot's 8-channel strip, 18 aligned float4 ----
  {
    const float4* gbase = reinterpret_cast<const float4*>(
        x + ((size_t)b * CDIM + ctile * 8) * DDIM);  // byte off b*4608+ctile*288: 16B aligned
    float4* xf4 = reinterpret_cast<float4*>(&xs[wv][0]);
    xf4[slot * 18 + cl] = gbase[cl];
    xf4[slot * 18 + cl + 8] = gbase[cl + 8];
    if (cl < 2) xf4[slot * 18 + cl + 16] = gbase[cl + 16];
  }
  __syncthreads();

  float xv[DDIM];
#pragma unroll
  for (int d = 0; d < DDIM; ++d)
    xv[d] = xs[wv][slot * 72 + cl * 9 + d];

  const float4* Tb = reinterpret_cast<const float4*>(T) + (size_t)e * NT * CDIM + c;

  float a0 = 0.f, a1 = 0.f, a2 = 0.f, a3 = 0.f;
  int t = 0;

  // order 3: a<=b2<=c3 (same enumeration order as the table build)
#pragma unroll
  for (int a = 0; a < DDIM; ++a) {
#pragma unroll
    for (int b2 = a; b2 < DDIM; ++b2) {
      const float xab = xv[a] * xv[b2];
#pragma unroll
      for (int c3 = b2; c3 < DDIM; ++c3) {
        const float m = xab * xv[c3];
        const float4 tv = Tb[(size_t)t * CDIM];
        a0 = fmaf(tv.x, m, a0);
        a1 = fmaf(tv.y, m, a1);
        a2 = fmaf(tv.z, m, a2);
        a3 = fmaf(tv.w, m, a3);
        ++t;
      }
    }
  }
  // order 2
#pragma unroll
  for (int a = 0; a < DDIM; ++a) {
#pragma unroll
    for (int b2 = a; b2 < DDIM; ++b2) {
      const float m = xv[a] * xv[b2];
      const float4 tv = Tb[(size_t)t * CDIM];
      a0 = fmaf(tv.x, m, a0);
      a1 = fmaf(tv.y, m, a1);
      a2 = fmaf(tv.z, m, a2);
      a3 = fmaf(tv.w, m, a3);
      ++t;
    }
  }
  // order 1
#pragma unroll
  for (int j = 0; j < DDIM; ++j) {
    const float m = xv[j];
    const float4 tv = Tb[(size_t)t * CDIM];
    a0 = fmaf(tv.x, m, a0);
    a1 = fmaf(tv.y, m, a1);
    a2 = fmaf(tv.z, m, a2);
    a3 = fmaf(tv.w, m, a3);
    ++t;
  }

  float4* o = reinterpret_cast<float4*>(out) + ((size_t)b * CDIM + c);
  *o = make_float4(a0, a1, a2, a3);
}

extern "C" void kernel_launch(void* const* d_in, const int* in_sizes, int n_in,
                              void* d_out, int out_size, void* d_ws, size_t ws_size,
                              hipStream_t stream) {
  const float* x     = (const float*)d_in[0];
  const float* y     = (const float*)d_in[1];
  const float* u1_0e = (const float*)d_in[2];
  const float* w1_0e = (const float*)d_in[3];
  const float* u2_0e = (const float*)d_in[4];
  const float* w2_0e = (const float*)d_in[5];
  const float* u3_0e = (const float*)d_in[6];
  const float* w3_0e = (const float*)d_in[7];
  const float* u1_1o = (const float*)d_in[8];
  const float* w1_1o = (const float*)d_in[9];
  const float* u2_1o = (const float*)d_in[10];
  const float* w2_1o = (const float*)d_in[11];
  const float* u3_1o = (const float*)d_in[12];
  const float* w3_1o = (const float*)d_in[13];

  float* T = (float*)d_ws;
  int* sortedB = (int*)((float*)d_ws + TABLE_FLOATS);
  int* esg = sortedB + BDIM;
  float* out = (float*)d_out;

  const size_t need = TABLE_FLOATS * sizeof(float) + 2 * BDIM * sizeof(int);
  if (ws_size < need) return;

  hipLaunchKernelGGL(table_bucket_kernel, dim3(EDIM * NT + 1), dim3(CDIM), 0, stream,
                     u1_0e, w1_0e, u2_0e, w2_0e, u3_0e, w3_0e,
                     u1_1o, w1_1o, u2_1o, w2_1o, u3_1o, w3_1o,
                     y, T, sortedB, esg);

  hipLaunchKernelGGL(symcon_main_kernel, dim3(256), dim3(256), 0, stream,
                     x, T, sortedB, esg, out);
}